// Round 15
// baseline (192.764 us; speedup 1.0000x reference)
//
#include <hip/hip_runtime.h>
#include <hip/hip_bf16.h>

// Problem constants
#define B_ 4
#define S_ 2048
#define D_ 128
#define H_ 8

typedef __attribute__((ext_vector_type(8))) short bf16x8;
typedef __attribute__((ext_vector_type(4))) float f32x4;

__device__ __forceinline__ short f2bf(float f) {
  union { float f; unsigned u; } v; v.f = f;
  unsigned u = v.u;
  unsigned r = (u + 0x7FFFu + ((u >> 16) & 1u)) >> 16;
  return (short)r;
}

// pack 4 fp32 -> 4 bf16 (RNE) as short4
__device__ __forceinline__ short4 pack4(f32x4 p) {
  union { __hip_bfloat162 h2[2]; short4 s4; } u;
  u.h2[0] = __float22bfloat162_rn(make_float2(p[0], p[1]));
  u.h2[1] = __float22bfloat162_rn(make_float2(p[2], p[3]));
  return u.s4;
}

// async global->LDS DMA, 16 B per lane. LDS dest = wave-uniform base + lane*16.
__device__ __forceinline__ void dma16(const short* g, short* l) {
  __builtin_amdgcn_global_load_lds(
      (const __attribute__((address_space(1))) unsigned int*)g,
      (__attribute__((address_space(3))) unsigned int*)l, 16, 0, 0);
}

// prep: transpose+convert W (128,1024) fp32 -> FRAGMENT-LINEAR bf16 image.
__global__ __launch_bounds__(256) void prep(
    const float* __restrict__ WQ, const float* __restrict__ WK, const float* __restrict__ WV,
    short* __restrict__ FQ, short* __restrict__ FK, short* __restrict__ FV) {
  __shared__ float tile[64][65];
  int bw = blockIdx.x >> 5;
  int tl = blockIdx.x & 31;
  int n0 = (tl & 15) * 64, k0 = (tl >> 4) * 64;
  const float* W = (bw == 0) ? WQ : (bw == 1) ? WK : WV;
  short* WF = (bw == 0) ? FQ : (bw == 1) ? FK : FV;
#pragma unroll
  for (int i = 0; i < 16; ++i) {
    int cix = threadIdx.x + 256 * i;
    int rr = cix >> 6, cc = cix & 63;
    tile[rr][cc] = W[(k0 + rr) * 1024 + n0 + cc];
  }
  __syncthreads();
#pragma unroll
  for (int i = 0; i < 16; ++i) {
    int cix = threadIdx.x + 256 * i;
    int rr = cix >> 6, cc = cix & 63;   // rr = n-local, cc = k-local
    int n = n0 + rr, k = k0 + cc;
    size_t off = (size_t)(n >> 7) * 16384
               + (size_t)(((n >> 4) & 7) * 4 + (k >> 5)) * 512
               + ((k >> 3) & 3) * 128 + (n & 15) * 8 + (k & 7);
    WF[off] = f2bf(tile[cc][rr]);
  }
}

// ---------------------------------------------------------------------------
// Tiled projection (r14, unchanged): pairing + reg-capped B + LDS-restage
// coalesced epilogue. Bit-identical outputs.
// ---------------------------------------------------------------------------
template <int MODE>
__device__ __forceinline__ void proj_pair(const float* __restrict__ X,
                                          const short* __restrict__ WF,
                                          const float* __restrict__ bias,
                                          short* __restrict__ out,
                                          int mtile, int np, short* sA) {
  int tid = threadIdx.x;
  int lane = tid & 63, w = tid >> 6;
  int l15 = lane & 15, l4 = lane >> 4;
  int m0 = mtile * 128;
  int bb = m0 >> 11;
  int mloc = m0 & 2047;

#pragma unroll
  for (int j = 0; j < 8; ++j) {
    int f = w * 8 + j;
    const float* src = X + (size_t)(m0 + (f >> 2) * 16 + l15) * 128 + (f & 3) * 32 + l4 * 8;
    float4 v0 = *(const float4*)src;
    float4 v1 = *(const float4*)(src + 4);
    union { struct { short4 lo, hi; } s; bf16x8 v; } u;
    u.s.lo = pack4((f32x4){v0.x, v0.y, v0.z, v0.w});
    u.s.hi = pack4((f32x4){v1.x, v1.y, v1.z, v1.w});
    *(bf16x8*)(sA + f * 512 + lane * 8) = u.v;
  }

  int wr = w >> 1, wc = w & 1;

  __syncthreads();

  bf16x8 a[4][4];
#pragma unroll
  for (int mi = 0; mi < 4; ++mi)
#pragma unroll
    for (int st = 0; st < 4; ++st)
      a[mi][st] = *(const bf16x8*)(sA + ((wr * 4 + mi) * 4 + st) * 512 + lane * 8);

#pragma unroll
  for (int nt = 0; nt < 2; ++nt) {
    int ntile = np * 2 + nt;
    int n0 = ntile * 128;

    const short* wfb = WF + (size_t)ntile * 16384 + wc * 8192 + lane * 8;

    f32x4 acc[4][4];
#pragma unroll
    for (int mi = 0; mi < 4; ++mi)
#pragma unroll
      for (int ni = 0; ni < 4; ++ni) acc[mi][ni] = (f32x4){0.f, 0.f, 0.f, 0.f};

#pragma unroll
    for (int ni = 0; ni < 4; ++ni) {
      bf16x8 bfr[4];
#pragma unroll
      for (int st = 0; st < 4; ++st)
        bfr[st] = *(const bf16x8*)(wfb + (ni * 4 + st) * 512);
#pragma unroll
      for (int mi = 0; mi < 4; ++mi) {
#pragma unroll
        for (int st = 0; st < 4; ++st) {
          if (MODE <= 1)
            acc[mi][ni] = __builtin_amdgcn_mfma_f32_16x16x32_bf16(bfr[st], a[mi][st], acc[mi][ni], 0, 0, 0);
          else
            acc[mi][ni] = __builtin_amdgcn_mfma_f32_16x16x32_bf16(a[mi][st], bfr[st], acc[mi][ni], 0, 0, 0);
        }
      }
    }

    __syncthreads();

    if (MODE == 0) {
#pragma unroll
      for (int mi = 0; mi < 4; ++mi) {
        int lrow = wr * 64 + mi * 16 + l15;
#pragma unroll
        for (int ni = 0; ni < 4; ++ni) {
          int d0 = wc * 64 + ni * 16 + l4 * 4;
          float4 bv = *(const float4*)(bias + n0 + d0);
          f32x4 t = acc[mi][ni];
          t[0] += bv.x; t[1] += bv.y; t[2] += bv.z; t[3] += bv.w;
          *(short4*)(sA + lrow * 128 + d0) = pack4(t);
        }
      }
    } else if (MODE == 1) {
#pragma unroll
      for (int mi = 0; mi < 4; ++mi) {
        int lk = wr * 64 + mi * 16 + l15;
        int kbase = (lk >> 6) * 8192 + ((lk >> 4) & 3) * 2048 + (lk & 15) * 8;
#pragma unroll
        for (int ni = 0; ni < 4; ++ni) {
          int d0 = wc * 64 + ni * 16 + l4 * 4;
          float4 bv = *(const float4*)(bias + n0 + d0);
          f32x4 t = acc[mi][ni];
          t[0] += bv.x; t[1] += bv.y; t[2] += bv.z; t[3] += bv.w;
          *(short4*)(sA + kbase + (d0 >> 5) * 512 + ((d0 >> 3) & 3) * 128 + (d0 & 7)) = pack4(t);
        }
      }
    } else {
#pragma unroll
      for (int ni = 0; ni < 4; ++ni) {
        int d = wc * 64 + ni * 16 + l15;
        float bvs = bias[n0 + d];
#pragma unroll
        for (int mi = 0; mi < 4; ++mi) {
          int ls0 = wr * 64 + mi * 16 + l4 * 4;
          f32x4 t = acc[mi][ni];
          t[0] += bvs; t[1] += bvs; t[2] += bvs; t[3] += bvs;
          *(short4*)(sA + (ls0 >> 6) * 8192
                        + ((d >> 4) * 2 + ((ls0 >> 5) & 1)) * 512
                        + ((ls0 >> 3) & 3) * 128 + (d & 15) * 8
                        + (ls0 & 7)) = pack4(t);
        }
      }
    }
    __syncthreads();

    short* gdst;
    if (MODE == 0)
      gdst = out + ((size_t)(bb * H_ + ntile) * S_ + mloc) * D_;
    else
      gdst = out + (size_t)(bb * H_ + ntile) * (S_ * D_) + (size_t)(mloc >> 6) * 8192;
#pragma unroll
    for (int i = 0; i < 8; ++i) {
      bf16x8 vv = *(const bf16x8*)(sA + (i * 256 + tid) * 8);
      *(bf16x8*)(gdst + (i * 256 + tid) * 8) = vv;
    }
  }
}

__global__ __launch_bounds__(256, 3) void proj3(
    const float* __restrict__ xq, const float* __restrict__ xk, const float* __restrict__ xv,
    const short* __restrict__ wtq, const short* __restrict__ wtk, const short* __restrict__ wtv,
    const float* __restrict__ bQ, const float* __restrict__ bK, const float* __restrict__ bV,
    short* __restrict__ Qp, short* __restrict__ Kf, short* __restrict__ Vf) {
  __shared__ short sA[16384];
  int work = (blockIdx.x & 7) * 96 + (blockIdx.x >> 3);
  int which = work >> 8;
  int t = work & 255;
  int mtile = t >> 2, np = t & 3;
  if (which == 0)      proj_pair<0>(xq, wtq, bQ, Qp, mtile, np, sA);
  else if (which == 1) proj_pair<1>(xk, wtk, bK, Kf, mtile, np, sA);
  else                 proj_pair<2>(xv, wtv, bV, Vf, mtile, np, sA);
}

// ---------------------------------------------------------------------------
// Flash attention r15: NO sP. P relayout done IN-REGISTER via ds_bpermute:
//   after QK+exp, lane (l15,l4) holds keys {m*16+4*l4+r}; PV A-frag u32 j needs
//   keys {8*l4+2j,+1} = u32 (j&1) of pk[m=l4>>1] from lane l15+32*(l4&1)+16*(j>>1)
//   -> 8 shfl + 4 cndmask per group, ap bytes IDENTICAL to the old LDS path.
// LDS 64 KB (K/V dbuf only) -> 2 blocks/CU: 4-wave/256-thread blocks, grid 512.
// Co-resident block pairs share bh (idx and idx+32 have same idx&3) -> same
// K/V stream. Per-CU DS/MFMA traffic unchanged vs r11; barrier stalls of one
// block now hidden by the other block's compute.
// ---------------------------------------------------------------------------
#define QK_H(KR)                                                               \
  _Pragma("unroll") for (int m = 0; m < 2; ++m) {                              \
    s0[m] = (f32x4){0.f, 0.f, 0.f, 0.f};                                       \
    s1[m] = (f32x4){0.f, 0.f, 0.f, 0.f};                                       \
    _Pragma("unroll") for (int st = 0; st < 4; ++st) {                         \
      s0[m] = __builtin_amdgcn_mfma_f32_16x16x32_bf16(KR[m * 4 + st], aq[0][st], s0[m], 0, 0, 0); \
      s1[m] = __builtin_amdgcn_mfma_f32_16x16x32_bf16(KR[m * 4 + st], aq[1][st], s1[m], 0, 0, 0); \
    }                                                                          \
  }

// exp2 + pack + in-register relayout for one q-group. S = s0/s1, LS = ls, AP out.
#define SM_X(S, LS, AP)                                                        \
  {                                                                            \
    _Pragma("unroll") for (int m = 0; m < 2; ++m) {                            \
      _Pragma("unroll") for (int r = 0; r < 4; ++r) {                          \
        float p = __builtin_amdgcn_exp2f(fabsf(S[m][r]) * SC2);                \
        LS += p;                                                               \
        S[m][r] = p;                                                           \
      }                                                                        \
    }                                                                          \
    short4 pk0_ = pack4(S[0]);                                                 \
    short4 pk1_ = pack4(S[1]);                                                 \
    int X0_ = ((int2*)&pk0_)->x, X1_ = ((int2*)&pk0_)->y;                      \
    int X2_ = ((int2*)&pk1_)->x, X3_ = ((int2*)&pk1_)->y;                      \
    int A0_ = __shfl(X0_, sb), B0_ = __shfl(X2_, sb);                          \
    int A1_ = __shfl(X1_, sb), B1_ = __shfl(X3_, sb);                          \
    int A2_ = __shfl(X0_, sb + 16), B2_ = __shfl(X2_, sb + 16);                \
    int A3_ = __shfl(X1_, sb + 16), B3_ = __shfl(X3_, sb + 16);                \
    union { int u[4]; bf16x8 v; } uu_;                                         \
    uu_.u[0] = hi_ ? B0_ : A0_;                                                \
    uu_.u[1] = hi_ ? B1_ : A1_;                                                \
    uu_.u[2] = hi_ ? B2_ : A2_;                                                \
    uu_.u[3] = hi_ ? B3_ : A3_;                                                \
    AP = uu_.v;                                                                \
  }

#define PV_H()                                                                 \
  _Pragma("unroll") for (int t8 = 0; t8 < 8; ++t8) {                           \
    o0[t8] = __builtin_amdgcn_mfma_f32_16x16x32_bf16(ap0, bv[t8], o0[t8], 0, 0, 0); \
    o1[t8] = __builtin_amdgcn_mfma_f32_16x16x32_bf16(ap1, bv[t8], o1[t8], 0, 0, 0); \
  }

__global__ __launch_bounds__(256, 2) void attn(const short* __restrict__ Qp,
                                               const short* __restrict__ Kf,
                                               const short* __restrict__ Vf,
                                               float* __restrict__ out) {
  __shared__ short sK0[8192], sK1[8192];  // 16 KB per buffer, frag-linear
  __shared__ short sV0[8192], sV1[8192];  // total 64 KB -> 2 blocks/CU

  int tid = threadIdx.x;
  int lane = tid & 63, w = tid >> 6;      // w = 0..3
  int xcd = blockIdx.x & 7;
  int idx = blockIdx.x >> 3;              // 0..63
  int bh  = xcd * 4 + (idx & 3);          // 0..31 (4 bh per XCD)
  int qt  = idx >> 2;                     // 0..15 (q-tiles of 128)
  int q0  = qt * 128;
  int l15 = lane & 15, l4 = lane >> 4;

  // shfl-exchange constants
  int sb = l15 + ((lane & 16) << 1);      // l15 + 32*(l4&1)
  bool hi_ = (lane >= 32);                // l4 >= 2 -> use pk1 (m=1) sources

  const short* Qbase = Qp + (size_t)bh * S_ * D_;
  const short* kgs = Kf + (size_t)bh * S_ * D_ + 4 * w * 512 + lane * 8;
  const short* vgs = Vf + (size_t)bh * S_ * D_ + 4 * w * 512 + lane * 8;

  // stage tile 0 -> buf0 (wave w stages frags 4w..4w+3 of K and V)
  dma16(kgs,        sK0 + 4 * w * 512);
  dma16(kgs + 512,  sK0 + (4 * w + 1) * 512);
  dma16(kgs + 1024, sK0 + (4 * w + 2) * 512);
  dma16(kgs + 1536, sK0 + (4 * w + 3) * 512);
  dma16(vgs,        sV0 + 4 * w * 512);
  dma16(vgs + 512,  sV0 + (4 * w + 1) * 512);
  dma16(vgs + 1024, sV0 + (4 * w + 2) * 512);
  dma16(vgs + 1536, sV0 + (4 * w + 3) * 512);

  // Q B-fragments for two 16-q groups (q = q0 + w*32 + g*16 + l15)
  bf16x8 aq[2][4];
#pragma unroll
  for (int g = 0; g < 2; ++g)
#pragma unroll
    for (int st = 0; st < 4; ++st)
      aq[g][st] = *(const bf16x8*)(Qbase + (q0 + w * 32 + g * 16 + l15) * D_ + l4 * 8 + 32 * st);

  f32x4 o0[8], o1[8];
#pragma unroll
  for (int t = 0; t < 8; ++t) {
    o0[t] = (f32x4){0.f, 0.f, 0.f, 0.f};
    o1[t] = (f32x4){0.f, 0.f, 0.f, 0.f};
  }
  float ls0 = 0.f, ls1 = 0.f;

  const float SC2 = 0.127530637f; // log2(e)/sqrt(128)

  __syncthreads();  // tile 0 ready

  for (int t = 0; t < 32; ++t) {
    const short* sKc = (t & 1) ? sK1 : sK0;
    const short* sVc = (t & 1) ? sV1 : sV0;
    if (t < 31) {
      short* sKn = (t & 1) ? sK0 : sK1;
      short* sVn = (t & 1) ? sV0 : sV1;
      const short* kn = kgs + (size_t)(t + 1) * 8192;
      const short* vn = vgs + (size_t)(t + 1) * 8192;
      dma16(kn,        sKn + 4 * w * 512);
      dma16(kn + 512,  sKn + (4 * w + 1) * 512);
      dma16(kn + 1024, sKn + (4 * w + 2) * 512);
      dma16(kn + 1536, sKn + (4 * w + 3) * 512);
      dma16(vn,        sVn + 4 * w * 512);
      dma16(vn + 512,  sVn + (4 * w + 1) * 512);
      dma16(vn + 1024, sVn + (4 * w + 2) * 512);
      dma16(vn + 1536, sVn + (4 * w + 3) * 512);
    }
    bf16x8 kA[8], kB[8], bv[8];
#pragma unroll
    for (int j = 0; j < 8; ++j)
      kA[j] = *(const bf16x8*)(sKc + j * 512 + lane * 8);
#pragma unroll
    for (int j = 0; j < 8; ++j)
      kB[j] = *(const bf16x8*)(sKc + 4096 + j * 512 + lane * 8);
#pragma unroll
    for (int j = 0; j < 8; ++j)
      bv[j] = *(const bf16x8*)(sVc + (2 * j) * 512 + lane * 8);
    __builtin_amdgcn_sched_barrier(0);

    f32x4 s0[2], s1[2];
    bf16x8 ap0, ap1;
    // half 0 (keys 0..31 of tile)
    __builtin_amdgcn_s_setprio(1);
    QK_H(kA);
    __builtin_amdgcn_s_setprio(0);
    SM_X(s0, ls0, ap0);
    SM_X(s1, ls1, ap1);
    __builtin_amdgcn_s_setprio(1);
    PV_H();
    __builtin_amdgcn_s_setprio(0);
    // half 1 (keys 32..63)
#pragma unroll
    for (int j = 0; j < 8; ++j)
      bv[j] = *(const bf16x8*)(sVc + (2 * j + 1) * 512 + lane * 8);
    __builtin_amdgcn_s_setprio(1);
    QK_H(kB);
    __builtin_amdgcn_s_setprio(0);
    SM_X(s0, ls0, ap0);
    SM_X(s1, ls1, ap1);
    __builtin_amdgcn_s_setprio(1);
    PV_H();
    __builtin_amdgcn_s_setprio(0);
    __syncthreads();
  }

  // final softmax denominators: per-lane partial sums -> quad reduce
  ls0 += __shfl_xor(ls0, 16);
  ls0 += __shfl_xor(ls0, 32);
  ls1 += __shfl_xor(ls1, 16);
  ls1 += __shfl_xor(ls1, 32);
  float inv0[4], inv1[4];
#pragma unroll
  for (int r = 0; r < 4; ++r) {
    inv0[r] = 1.f / __shfl(ls0, l4 * 4 + r);
    inv1[r] = 1.f / __shfl(ls1, l4 * 4 + r);
  }

  // epilogue: out[b, q, h*128 + dv] fp32
  int bb = bh >> 3, h = bh & 7;
#pragma unroll
  for (int t = 0; t < 8; ++t) {
#pragma unroll
    for (int r = 0; r < 4; ++r) {
      int qA = q0 + w * 32 + l4 * 4 + r;
      int qB = qA + 16;
      out[((size_t)(bb * S_ + qA)) * (H_ * D_) + h * D_ + t * 16 + l15] = o0[t][r] * inv0[r];
      out[((size_t)(bb * S_ + qB)) * (H_ * D_) + h * D_ + t * 16 + l15] = o1[t][r] * inv1[r];
    }
  }
}

extern "C" void kernel_launch(void* const* d_in, const int* in_sizes, int n_in,
                              void* d_out, int out_size, void* d_ws, size_t ws_size,
                              hipStream_t stream) {
  (void)in_sizes; (void)n_in; (void)out_size; (void)ws_size;
  const float* q  = (const float*)d_in[0];
  const float* k  = (const float*)d_in[1];
  const float* v  = (const float*)d_in[2];
  const float* WQ = (const float*)d_in[3];
  const float* bQ = (const float*)d_in[4];
  const float* WK = (const float*)d_in[5];
  const float* bK = (const float*)d_in[6];
  const float* WV = (const float*)d_in[7];
  const float* bV = (const float*)d_in[8];

  const int NW = D_ * H_ * D_;      // 131072 per weight
  const int NP = B_ * H_ * S_ * D_; // 8388608 per projected tensor

  short* ws  = (short*)d_ws;
  short* wtq = ws;
  short* wtk = wtq + NW;
  short* wtv = wtk + NW;
  short* Qp  = wtv + NW;
  short* Kf  = Qp + NP;
  short* Vf  = Kf + NP;

  prep<<<96, 256, 0, stream>>>(WQ, WK, WV, wtq, wtk, wtv);

  proj3<<<768, 256, 0, stream>>>(q, k, v, wtq, wtk, wtv, bQ, bK, bV, Qp, Kf, Vf);

  attn<<<512, 256, 0, stream>>>(Qp, Kf, Vf, (float*)d_out);
}

// Round 16
// 175.823 us; speedup vs baseline: 1.0964x; 1.0964x over previous
//
#include <hip/hip_runtime.h>
#include <hip/hip_bf16.h>

// Problem constants
#define B_ 4
#define S_ 2048
#define D_ 128
#define H_ 8

typedef __attribute__((ext_vector_type(8))) short bf16x8;
typedef __attribute__((ext_vector_type(4))) float f32x4;

__device__ __forceinline__ short f2bf(float f) {
  union { float f; unsigned u; } v; v.f = f;
  unsigned u = v.u;
  unsigned r = (u + 0x7FFFu + ((u >> 16) & 1u)) >> 16;
  return (short)r;
}

// pack 4 fp32 -> 4 bf16 (RNE) as short4
__device__ __forceinline__ short4 pack4(f32x4 p) {
  union { __hip_bfloat162 h2[2]; short4 s4; } u;
  u.h2[0] = __float22bfloat162_rn(make_float2(p[0], p[1]));
  u.h2[1] = __float22bfloat162_rn(make_float2(p[2], p[3]));
  return u.s4;
}

// async global->LDS DMA, 16 B per lane. LDS dest = wave-uniform base + lane*16.
__device__ __forceinline__ void dma16(const short* g, short* l) {
  __builtin_amdgcn_global_load_lds(
      (const __attribute__((address_space(1))) unsigned int*)g,
      (__attribute__((address_space(3))) unsigned int*)l, 16, 0, 0);
}

// prep: transpose+convert W (128,1024) fp32 -> FRAGMENT-LINEAR bf16 image:
//   WF[ntile][f][lane][e], f = ((n>>4)&7)*4 + (k>>5), lane = ((k>>3)&3)*16 + (n&15),
//   e = k&7.  proj reads its B-frags as contiguous 1 KB wave-loads from L2.
__global__ __launch_bounds__(256) void prep(
    const float* __restrict__ WQ, const float* __restrict__ WK, const float* __restrict__ WV,
    short* __restrict__ FQ, short* __restrict__ FK, short* __restrict__ FV) {
  __shared__ float tile[64][65];
  int bw = blockIdx.x >> 5;
  int tl = blockIdx.x & 31;
  int n0 = (tl & 15) * 64, k0 = (tl >> 4) * 64;
  const float* W = (bw == 0) ? WQ : (bw == 1) ? WK : WV;
  short* WF = (bw == 0) ? FQ : (bw == 1) ? FK : FV;
#pragma unroll
  for (int i = 0; i < 16; ++i) {
    int cix = threadIdx.x + 256 * i;
    int rr = cix >> 6, cc = cix & 63;
    tile[rr][cc] = W[(k0 + rr) * 1024 + n0 + cc];
  }
  __syncthreads();
#pragma unroll
  for (int i = 0; i < 16; ++i) {
    int cix = threadIdx.x + 256 * i;
    int rr = cix >> 6, cc = cix & 63;   // rr = n-local, cc = k-local
    int n = n0 + rr, k = k0 + cc;
    size_t off = (size_t)(n >> 7) * 16384
               + (size_t)(((n >> 4) & 7) * 4 + (k >> 5)) * 512
               + ((k >> 3) & 3) * 128 + (n & 15) * 8 + (k & 7);
    WF[off] = f2bf(tile[cc][rr]);
  }
}

// ---------------------------------------------------------------------------
// Tiled projection (r14 best): pairing + reg-capped B + LDS-restage coalesced
// epilogue.  Block = 128(M) x 256(N: 2 ntiles) x K=128; A staged once to
// fragment-order LDS; B as bfr[4] per-ni (peak VGPR ~164, no spill at 3/CU);
// results restaged to sA at local image offsets then copied LDS->global in
// pure linear order (8 x b128/thread -> 1 KB/wave stores).
// ---------------------------------------------------------------------------
template <int MODE>
__device__ __forceinline__ void proj_pair(const float* __restrict__ X,
                                          const short* __restrict__ WF,
                                          const float* __restrict__ bias,
                                          short* __restrict__ out,
                                          int mtile, int np, short* sA) {
  int tid = threadIdx.x;
  int lane = tid & 63, w = tid >> 6;
  int l15 = lane & 15, l4 = lane >> 4;
  int m0 = mtile * 128;
  int bb = m0 >> 11;
  int mloc = m0 & 2047;

#pragma unroll
  for (int j = 0; j < 8; ++j) {
    int f = w * 8 + j;
    const float* src = X + (size_t)(m0 + (f >> 2) * 16 + l15) * 128 + (f & 3) * 32 + l4 * 8;
    float4 v0 = *(const float4*)src;
    float4 v1 = *(const float4*)(src + 4);
    union { struct { short4 lo, hi; } s; bf16x8 v; } u;
    u.s.lo = pack4((f32x4){v0.x, v0.y, v0.z, v0.w});
    u.s.hi = pack4((f32x4){v1.x, v1.y, v1.z, v1.w});
    *(bf16x8*)(sA + f * 512 + lane * 8) = u.v;
  }

  int wr = w >> 1, wc = w & 1;

  __syncthreads();

  bf16x8 a[4][4];
#pragma unroll
  for (int mi = 0; mi < 4; ++mi)
#pragma unroll
    for (int st = 0; st < 4; ++st)
      a[mi][st] = *(const bf16x8*)(sA + ((wr * 4 + mi) * 4 + st) * 512 + lane * 8);

#pragma unroll
  for (int nt = 0; nt < 2; ++nt) {
    int ntile = np * 2 + nt;
    int n0 = ntile * 128;

    const short* wfb = WF + (size_t)ntile * 16384 + wc * 8192 + lane * 8;

    f32x4 acc[4][4];
#pragma unroll
    for (int mi = 0; mi < 4; ++mi)
#pragma unroll
      for (int ni = 0; ni < 4; ++ni) acc[mi][ni] = (f32x4){0.f, 0.f, 0.f, 0.f};

#pragma unroll
    for (int ni = 0; ni < 4; ++ni) {
      bf16x8 bfr[4];
#pragma unroll
      for (int st = 0; st < 4; ++st)
        bfr[st] = *(const bf16x8*)(wfb + (ni * 4 + st) * 512);
#pragma unroll
      for (int mi = 0; mi < 4; ++mi) {
#pragma unroll
        for (int st = 0; st < 4; ++st) {
          if (MODE <= 1)
            acc[mi][ni] = __builtin_amdgcn_mfma_f32_16x16x32_bf16(bfr[st], a[mi][st], acc[mi][ni], 0, 0, 0);
          else
            acc[mi][ni] = __builtin_amdgcn_mfma_f32_16x16x32_bf16(a[mi][st], bfr[st], acc[mi][ni], 0, 0, 0);
        }
      }
    }

    // Barrier: nt=0 -> all waves' a[] reads done (sA now dead);
    //          nt=1 -> all waves' prior copy reads done.
    __syncthreads();

    // Restage into sA at LOCAL image offsets (bias + RNE pack, as before).
    if (MODE == 0) {
      // local [row 0..127][d 0..127] row-major
#pragma unroll
      for (int mi = 0; mi < 4; ++mi) {
        int lrow = wr * 64 + mi * 16 + l15;
#pragma unroll
        for (int ni = 0; ni < 4; ++ni) {
          int d0 = wc * 64 + ni * 16 + l4 * 4;
          float4 bv = *(const float4*)(bias + n0 + d0);
          f32x4 t = acc[mi][ni];
          t[0] += bv.x; t[1] += bv.y; t[2] += bv.z; t[3] += bv.w;
          *(short4*)(sA + lrow * 128 + d0) = pack4(t);
        }
      }
    } else if (MODE == 1) {
      // local K image: 2 chunks x 16 frags x 512
#pragma unroll
      for (int mi = 0; mi < 4; ++mi) {
        int lk = wr * 64 + mi * 16 + l15;
        int kbase = (lk >> 6) * 8192 + ((lk >> 4) & 3) * 2048 + (lk & 15) * 8;
#pragma unroll
        for (int ni = 0; ni < 4; ++ni) {
          int d0 = wc * 64 + ni * 16 + l4 * 4;
          float4 bv = *(const float4*)(bias + n0 + d0);
          f32x4 t = acc[mi][ni];
          t[0] += bv.x; t[1] += bv.y; t[2] += bv.z; t[3] += bv.w;
          *(short4*)(sA + kbase + (d0 >> 5) * 512 + ((d0 >> 3) & 3) * 128 + (d0 & 7)) = pack4(t);
        }
      }
    } else {
      // local V image: 2 chunks x 16 frags x 512
#pragma unroll
      for (int ni = 0; ni < 4; ++ni) {
        int d = wc * 64 + ni * 16 + l15;
        float bvs = bias[n0 + d];
#pragma unroll
        for (int mi = 0; mi < 4; ++mi) {
          int ls0 = wr * 64 + mi * 16 + l4 * 4;
          f32x4 t = acc[mi][ni];
          t[0] += bvs; t[1] += bvs; t[2] += bvs; t[3] += bvs;
          *(short4*)(sA + (ls0 >> 6) * 8192
                        + ((d >> 4) * 2 + ((ls0 >> 5) & 1)) * 512
                        + ((ls0 >> 3) & 3) * 128 + (d & 15) * 8
                        + (ls0 & 7)) = pack4(t);
        }
      }
    }
    __syncthreads();  // image complete

    // Linear coalesced copy: 32 KB, identity order. 8 x b128 per thread;
    // consecutive lanes -> consecutive 16 B -> 1 KB per wave-store.
    short* gdst;
    if (MODE == 0)
      gdst = out + ((size_t)(bb * H_ + ntile) * S_ + mloc) * D_;
    else
      gdst = out + (size_t)(bb * H_ + ntile) * (S_ * D_) + (size_t)(mloc >> 6) * 8192;
#pragma unroll
    for (int i = 0; i < 8; ++i) {
      bf16x8 vv = *(const bf16x8*)(sA + (i * 256 + tid) * 8);
      *(bf16x8*)(gdst + (i * 256 + tid) * 8) = vv;
    }
  }
}

// 768 blocks = 3 projs x 64 mtiles x 4 npairs, npair fastest, XCD-chunked (96/XCD).
__global__ __launch_bounds__(256, 3) void proj3(
    const float* __restrict__ xq, const float* __restrict__ xk, const float* __restrict__ xv,
    const short* __restrict__ wtq, const short* __restrict__ wtk, const short* __restrict__ wtv,
    const float* __restrict__ bQ, const float* __restrict__ bK, const float* __restrict__ bV,
    short* __restrict__ Qp, short* __restrict__ Kf, short* __restrict__ Vf) {
  __shared__ short sA[16384];
  int work = (blockIdx.x & 7) * 96 + (blockIdx.x >> 3);
  int which = work >> 8;           // 256 works per projection
  int t = work & 255;
  int mtile = t >> 2, np = t & 3;
  if (which == 0)      proj_pair<0>(xq, wtq, bQ, Qp, mtile, np, sA);
  else if (which == 1) proj_pair<1>(xk, wtk, bK, Kf, mtile, np, sA);
  else                 proj_pair<2>(xv, wtv, bV, Vf, mtile, np, sA);
}

// Flash-style attention with |score| softmax, NO max tracking.
// r11/r14 attn (session best: 82.2 µs): block-shared LDS K/V double-buffer,
// 8 waves, grid 256 (1 block/CU), split P regions (pw0/pw1).
#define PSTR 72  // P row stride (shorts)

#define QK_H(KR)                                                               \
  _Pragma("unroll") for (int m = 0; m < 2; ++m) {                              \
    s0[m] = (f32x4){0.f, 0.f, 0.f, 0.f};                                       \
    s1[m] = (f32x4){0.f, 0.f, 0.f, 0.f};                                       \
    _Pragma("unroll") for (int st = 0; st < 4; ++st) {                         \
      s0[m] = __builtin_amdgcn_mfma_f32_16x16x32_bf16(KR[m * 4 + st], aq[0][st], s0[m], 0, 0, 0); \
      s1[m] = __builtin_amdgcn_mfma_f32_16x16x32_bf16(KR[m * 4 + st], aq[1][st], s1[m], 0, 0, 0); \
    }                                                                          \
  }

#define SM_H()                                                                 \
  _Pragma("unroll") for (int m = 0; m < 2; ++m) {                              \
    _Pragma("unroll") for (int r = 0; r < 4; ++r) {                            \
      float p = __builtin_amdgcn_exp2f(fabsf(s0[m][r]) * SC2);                 \
      ls0 += p;                                                                \
      s0[m][r] = p;                                                            \
    }                                                                          \
    *(short4*)(pw0 + l15 * PSTR + m * 16 + l4 * 4) = pack4(s0[m]);             \
  }                                                                            \
  _Pragma("unroll") for (int m = 0; m < 2; ++m) {                              \
    _Pragma("unroll") for (int r = 0; r < 4; ++r) {                            \
      float p = __builtin_amdgcn_exp2f(fabsf(s1[m][r]) * SC2);                 \
      ls1 += p;                                                                \
      s1[m][r] = p;                                                            \
    }                                                                          \
    *(short4*)(pw1 + l15 * PSTR + m * 16 + l4 * 4) = pack4(s1[m]);             \
  }                                                                            \
  ap0 = *(const bf16x8*)(pw0 + l15 * PSTR + l4 * 8);                           \
  ap1 = *(const bf16x8*)(pw1 + l15 * PSTR + l4 * 8);

#define PV_H()                                                                 \
  _Pragma("unroll") for (int t8 = 0; t8 < 8; ++t8) {                           \
    o0[t8] = __builtin_amdgcn_mfma_f32_16x16x32_bf16(ap0, bv[t8], o0[t8], 0, 0, 0); \
    o1[t8] = __builtin_amdgcn_mfma_f32_16x16x32_bf16(ap1, bv[t8], o1[t8], 0, 0, 0); \
  }

__global__ __launch_bounds__(512, 2) void attn(const short* __restrict__ Qp,
                                               const short* __restrict__ Kf,
                                               const short* __restrict__ Vf,
                                               float* __restrict__ out) {
  __shared__ short sK0[8192], sK1[8192];  // 16 KB per buffer, frag-linear
  __shared__ short sV0[8192], sV1[8192];
  __shared__ short sP[16 * 16 * PSTR];    // per-wave DOUBLE P region (36 KB)

  int tid = threadIdx.x;
  int lane = tid & 63, w = tid >> 6;      // w = 0..7
  int xcd = blockIdx.x & 7;
  int idx = blockIdx.x >> 3;              // 0..31
  int bh  = xcd * 4 + (idx & 3);          // 0..31
  int qt  = idx >> 2;                     // 0..7 (q-tiles of 256)
  int q0  = qt * 256;
  int l15 = lane & 15, l4 = lane >> 4;

  const short* Qbase = Qp + (size_t)bh * S_ * D_;
  const short* kgs = Kf + (size_t)bh * S_ * D_ + 2 * w * 512 + lane * 8;
  const short* vgs = Vf + (size_t)bh * S_ * D_ + 2 * w * 512 + lane * 8;

  // stage tile 0 -> buf0 (wave w stages frags 2w, 2w+1 of K and V)
  dma16(kgs,       sK0 + 2 * w * 512);
  dma16(kgs + 512, sK0 + (2 * w + 1) * 512);
  dma16(vgs,       sV0 + 2 * w * 512);
  dma16(vgs + 512, sV0 + (2 * w + 1) * 512);

  // Q B-fragments for two 16-q groups (q = q0 + w*32 + g*16 + l15)
  bf16x8 aq[2][4];
#pragma unroll
  for (int g = 0; g < 2; ++g)
#pragma unroll
    for (int st = 0; st < 4; ++st)
      aq[g][st] = *(const bf16x8*)(Qbase + (q0 + w * 32 + g * 16 + l15) * D_ + l4 * 8 + 32 * st);

  f32x4 o0[8], o1[8];
#pragma unroll
  for (int t = 0; t < 8; ++t) {
    o0[t] = (f32x4){0.f, 0.f, 0.f, 0.f};
    o1[t] = (f32x4){0.f, 0.f, 0.f, 0.f};
  }
  float ls0 = 0.f, ls1 = 0.f;

  const float SC2 = 0.127530637f; // log2(e)/sqrt(128)
  short* pw0 = sP + w * 16 * PSTR;
  short* pw1 = sP + (8 + w) * 16 * PSTR;

  __syncthreads();  // tile 0 ready

  for (int t = 0; t < 32; ++t) {
    const short* sKc = (t & 1) ? sK1 : sK0;
    const short* sVc = (t & 1) ? sV1 : sV0;
    if (t < 31) {
      short* sKn = (t & 1) ? sK0 : sK1;
      short* sVn = (t & 1) ? sV0 : sV1;
      const short* kn = kgs + (size_t)(t + 1) * 8192;
      const short* vn = vgs + (size_t)(t + 1) * 8192;
      dma16(kn,       sKn + 2 * w * 512);
      dma16(kn + 512, sKn + (2 * w + 1) * 512);
      dma16(vn,       sVn + 2 * w * 512);
      dma16(vn + 512, sVn + (2 * w + 1) * 512);
    }
    bf16x8 kA[8], kB[8], bv[8];
#pragma unroll
    for (int j = 0; j < 8; ++j)
      kA[j] = *(const bf16x8*)(sKc + j * 512 + lane * 8);
#pragma unroll
    for (int j = 0; j < 8; ++j)
      kB[j] = *(const bf16x8*)(sKc + 4096 + j * 512 + lane * 8);
#pragma unroll
    for (int j = 0; j < 8; ++j)
      bv[j] = *(const bf16x8*)(sVc + (2 * j) * 512 + lane * 8);
    __builtin_amdgcn_sched_barrier(0);

    f32x4 s0[2], s1[2];
    bf16x8 ap0, ap1;
    // half 0
    __builtin_amdgcn_s_setprio(1);
    QK_H(kA);
    __builtin_amdgcn_s_setprio(0);
    SM_H();
    __builtin_amdgcn_s_setprio(1);
    PV_H();
    __builtin_amdgcn_s_setprio(0);
    // half 1
#pragma unroll
    for (int j = 0; j < 8; ++j)
      bv[j] = *(const bf16x8*)(sVc + (2 * j + 1) * 512 + lane * 8);
    __builtin_amdgcn_s_setprio(1);
    QK_H(kB);
    __builtin_amdgcn_s_setprio(0);
    SM_H();
    __builtin_amdgcn_s_setprio(1);
    PV_H();
    __builtin_amdgcn_s_setprio(0);
    __syncthreads();
  }

  // final softmax denominators: per-lane partial sums -> quad reduce
  ls0 += __shfl_xor(ls0, 16);
  ls0 += __shfl_xor(ls0, 32);
  ls1 += __shfl_xor(ls1, 16);
  ls1 += __shfl_xor(ls1, 32);
  float inv0[4], inv1[4];
#pragma unroll
  for (int r = 0; r < 4; ++r) {
    inv0[r] = 1.f / __shfl(ls0, l4 * 4 + r);
    inv1[r] = 1.f / __shfl(ls1, l4 * 4 + r);
  }

  // epilogue: out[b, q, h*128 + dv] fp32
  int bb = bh >> 3, h = bh & 7;
#pragma unroll
  for (int t = 0; t < 8; ++t) {
#pragma unroll
    for (int r = 0; r < 4; ++r) {
      int qA = q0 + w * 32 + l4 * 4 + r;
      int qB = qA + 16;
      out[((size_t)(bb * S_ + qA)) * (H_ * D_) + h * D_ + t * 16 + l15] = o0[t][r] * inv0[r];
      out[((size_t)(bb * S_ + qB)) * (H_ * D_) + h * D_ + t * 16 + l15] = o1[t][r] * inv1[r];
    }
  }
}

extern "C" void kernel_launch(void* const* d_in, const int* in_sizes, int n_in,
                              void* d_out, int out_size, void* d_ws, size_t ws_size,
                              hipStream_t stream) {
  (void)in_sizes; (void)n_in; (void)out_size; (void)ws_size;
  const float* q  = (const float*)d_in[0];
  const float* k  = (const float*)d_in[1];
  const float* v  = (const float*)d_in[2];
  const float* WQ = (const float*)d_in[3];
  const float* bQ = (const float*)d_in[4];
  const float* WK = (const float*)d_in[5];
  const float* bK = (const float*)d_in[6];
  const float* WV = (const float*)d_in[7];
  const float* bV = (const float*)d_in[8];

  const int NW = D_ * H_ * D_;      // 131072 per weight
  const int NP = B_ * H_ * S_ * D_; // 8388608 per projected tensor

  short* ws  = (short*)d_ws;
  short* wtq = ws;
  short* wtk = wtq + NW;
  short* wtv = wtk + NW;
  short* Qp  = wtv + NW;
  short* Kf  = Qp + NP;
  short* Vf  = Kf + NP;

  prep<<<96, 256, 0, stream>>>(WQ, WK, WV, wtq, wtk, wtv);

  proj3<<<768, 256, 0, stream>>>(q, k, v, wtq, wtk, wtv, bQ, bK, bV, Qp, Kf, Vf);

  attn<<<256, 512, 0, stream>>>(Qp, Kf, Vf, (float*)d_out);
}